// Round 15
// baseline (555.627 us; speedup 1.0000x reference)
//
#include <hip/hip_runtime.h>
#include <cstddef>

typedef __attribute__((ext_vector_type(8))) short bf16x8;
typedef __attribute__((ext_vector_type(4))) float f32x4;
typedef __attribute__((ext_vector_type(2))) float f32x2;
typedef __attribute__((ext_vector_type(4))) short short4v;
typedef unsigned long long u64;
typedef unsigned int u32;
typedef unsigned short u16;

#define MFMA16 __builtin_amdgcn_mfma_f32_16x16x32_bf16
static constexpr float LN_EPS = 1e-5f;
static constexpr float L2E = 1.44269504f;

__device__ __forceinline__ u16 f2bf(float f) {
    u32 u = __builtin_bit_cast(u32, f);
    return (u16)((u + 0x7FFFu + ((u >> 16) & 1u)) >> 16);
}
__device__ __forceinline__ float bf2f(u16 h) {
    u32 u = ((u32)h) << 16;
    return __builtin_bit_cast(float, u);
}

// ---------------- block-wide sum (256 threads) ----------------
__device__ __forceinline__ float block_sum256(float v) {
    __shared__ float sc[4];
    #pragma unroll
    for (int o = 32; o > 0; o >>= 1) v += __shfl_down(v, o);
    if ((threadIdx.x & 63) == 0) sc[threadIdx.x >> 6] = v;
    __syncthreads();
    v = sc[0] + sc[1] + sc[2] + sc[3];
    __syncthreads();
    return v;
}

// ---------------- prep: weights fp32 [k][n] -> bf16 Wt [mat][n][k] ----------------
__global__ __launch_bounds__(256) void prepw_kernel(
    const float* __restrict__ wq, const float* __restrict__ wk,
    const float* __restrict__ wv, const float* __restrict__ wo,
    u16* __restrict__ wt)
{
    const int mat = blockIdx.z;
    const float* W = mat == 0 ? wq : mat == 1 ? wk : mat == 2 ? wv : wo;
    const int k0 = blockIdx.x * 64, n0 = blockIdx.y * 64;
    __shared__ u16 ld[64][72];
    const int t = threadIdx.x;
    {
        const int kk = t >> 2;
        #pragma unroll
        for (int j = 0; j < 4; ++j) {
            const int nn = ((t & 3) + j * 4) * 4;
            float4 x = *(const float4*)&W[(size_t)(k0 + kk) * 512 + n0 + nn];
            ld[kk][nn + 0] = f2bf(x.x); ld[kk][nn + 1] = f2bf(x.y);
            ld[kk][nn + 2] = f2bf(x.z); ld[kk][nn + 3] = f2bf(x.w);
        }
    }
    __syncthreads();
    {
        const int n = t & 63, kc = (t >> 6) * 16;
        u16* op = wt + ((size_t)mat * 512 + n0 + n) * 512 + k0 + kc;
        #pragma unroll
        for (int j = 0; j < 4; ++j) {
            short4v v;
            v[0] = ld[kc + j*4 + 0][n]; v[1] = ld[kc + j*4 + 1][n];
            v[2] = ld[kc + j*4 + 2][n]; v[3] = ld[kc + j*4 + 3][n];
            *(short4v*)(op + j * 4) = v;
        }
    }
}

// ---------------- K1: projections via MFMA. X fp32 @ Wt -> Qh/Kh bf16 [bh][s][64], V -> Vt [bh][64][2048]
__global__ __launch_bounds__(256) void proj_kernel(
    const float* __restrict__ qin, const float* __restrict__ kin, const float* __restrict__ vin,
    const u16* __restrict__ wt,
    u16* __restrict__ Qh, u16* __restrict__ Kh, u16* __restrict__ Vt)
{
    const int z = blockIdx.z;
    const float* X = z == 0 ? qin : (z == 1 ? kin : vin);
    const u16* W = wt + (size_t)z * 512 * 512;
    const int m0 = blockIdx.x * 64;
    const int h = blockIdx.y;
    const int t = threadIdx.x, l = t & 63, w = t >> 6;
    const int q = l & 15, G = l >> 4;
    const int wr = w >> 1, wc = w & 1;

    f32x4 acc[2][2] = {};
    for (int k0 = 0; k0 < 512; k0 += 32) {
        bf16x8 af[2], bfr[2];
        #pragma unroll
        for (int mi = 0; mi < 2; ++mi) {
            const float* xp = X + (size_t)(m0 + wr*32 + mi*16 + q) * 512 + k0 + G*8;
            float4 x0 = *(const float4*)xp;
            float4 x1 = *(const float4*)(xp + 4);
            bf16x8 a;
            a[0] = f2bf(x0.x); a[1] = f2bf(x0.y); a[2] = f2bf(x0.z); a[3] = f2bf(x0.w);
            a[4] = f2bf(x1.x); a[5] = f2bf(x1.y); a[6] = f2bf(x1.z); a[7] = f2bf(x1.w);
            af[mi] = a;
        }
        #pragma unroll
        for (int tn = 0; tn < 2; ++tn)
            bfr[tn] = *(const bf16x8*)(W + (size_t)(h*64 + wc*32 + tn*16 + q) * 512 + k0 + G*8);
        #pragma unroll
        for (int mi = 0; mi < 2; ++mi)
            #pragma unroll
            for (int tn = 0; tn < 2; ++tn)
                acc[mi][tn] = MFMA16(af[mi], bfr[tn], acc[mi][tn], 0, 0, 0);
    }
    if (z == 2) {
        // V: write transposed directly -> Vt[bh][d][s], 4 consecutive s per lane (8B)
        #pragma unroll
        for (int mi = 0; mi < 2; ++mi)
            #pragma unroll
            for (int tn = 0; tn < 2; ++tn) {
                const int d = wc*32 + tn*16 + q;
                const int m = m0 + wr*32 + mi*16 + G*4;
                const int bb = m >> 11, s = m & 2047;
                short4v sv;
                #pragma unroll
                for (int r = 0; r < 4; ++r) sv[r] = (short)f2bf(acc[mi][tn][r]);
                *(short4v*)&Vt[(((size_t)(bb*8 + h) << 6) + d) * 2048 + s] = sv;
            }
    } else {
        u16* O = z == 0 ? Qh : Kh;
        const float scv = (z == 0) ? 0.125f : 1.0f;   // fold 1/sqrt(64) into Q (exact pow2)
        #pragma unroll
        for (int mi = 0; mi < 2; ++mi)
            #pragma unroll
            for (int tn = 0; tn < 2; ++tn)
                #pragma unroll
                for (int r = 0; r < 4; ++r) {
                    const int m = m0 + wr*32 + mi*16 + G*4 + r;
                    const int bb = m >> 11, s = m & 2047;
                    const int d = wc*32 + tn*16 + q;
                    O[(((size_t)(bb*8 + h) << 11) + s) * 64 + d] = f2bf(acc[mi][tn][r] * scv);
                }
    }
}

// ---------------- maskrow: fused mask bit-pack + rowsums (overlap mask HBM with MFMA) ----------------
// grid (128, 4) = 512 blocks (2/CU). Block = 16 q-rows of batch bb, all 8 heads.
// Phase A: ballot-pack 16 mask rows -> LDS + global bits (mask read once: rows shared by heads).
// Phase B: wave w computes rowsums for heads 2w,2w+1; K frags direct from global (L2-resident).
__global__ __launch_bounds__(256) void maskrow_kernel(
    const int* __restrict__ mask, const u16* __restrict__ Qh, const u16* __restrict__ Kh,
    u64* __restrict__ bits, float* __restrict__ invs)
{
    const int rg = blockIdx.x;            // 16-row group
    const int bb = blockIdx.y;
    const int rbase = rg * 16;
    const int t = threadIdx.x, l = t & 63, w = t >> 6;
    const int q = l & 15, G = l >> 4;
    __shared__ u64 mbits[16][33];         // +1 pad: conflict-free mbits[q][kt] reads

    // ---- Phase A: pack 16 rows of mask (each wave: 4 rows) ----
    #pragma unroll
    for (int rp = 0; rp < 4; ++rp) {
        const int r = rp * 4 + w;
        const int* mrow = mask + ((((size_t)bb << 11) + rbase + r) << 11);
        u64* brow = bits + ((((size_t)bb << 11) + rbase + r) << 5);
        #pragma unroll 8
        for (int it = 0; it < 32; ++it) {
            u64 bset = __ballot(mrow[it * 64 + l] != 0);
            if (l == 0) { mbits[r][it] = bset; brow[it] = bset; }
        }
    }
    __syncthreads();

    // ---- Phase B: rowsums, 2 heads per wave ----
    bf16x8 qf[2][2];
    #pragma unroll
    for (int hp = 0; hp < 2; ++hp) {
        const int bh = bb * 8 + w * 2 + hp;
        const size_t qb = (((size_t)bh << 11) + rbase + q) * 64;
        qf[hp][0] = *(const bf16x8*)(Qh + qb + G*8);
        qf[hp][1] = *(const bf16x8*)(Qh + qb + 32 + G*8);
    }
    float rs[2] = {0.f, 0.f};
    for (int kt = 0; kt < 32; ++kt) {
        const u64 mw = mbits[q][kt];
        #pragma unroll
        for (int hp = 0; hp < 2; ++hp) {
            const int bh = bb * 8 + w * 2 + hp;
            f32x4 acc[4] = {};
            #pragma unroll
            for (int mt = 0; mt < 4; ++mt) {
                const size_t kb = ((((size_t)bh << 11) + kt*64 + mt*16 + q) * 64) + G*8;
                bf16x8 k0 = *(const bf16x8*)(Kh + kb);
                bf16x8 k1 = *(const bf16x8*)(Kh + kb + 32);
                acc[mt] = MFMA16(k0, qf[hp][0], acc[mt], 0, 0, 0);
                acc[mt] = MFMA16(k1, qf[hp][1], acc[mt], 0, 0, 0);
            }
            #pragma unroll
            for (int mt = 0; mt < 4; ++mt)
                #pragma unroll
                for (int r = 0; r < 4; ++r) {
                    const int c = mt*16 + G*4 + r;
                    rs[hp] += ((mw >> c) & 1) ? 0.f : exp2f(acc[mt][r] * L2E);
                }
        }
    }
    #pragma unroll
    for (int hp = 0; hp < 2; ++hp) {
        rs[hp] += __shfl_xor(rs[hp], 16);
        rs[hp] += __shfl_xor(rs[hp], 32);
        const int bh = bb * 8 + w * 2 + hp;
        if (G == 0) invs[((size_t)bh << 11) + rbase + q] = 1.0f / rs[hp];
    }
}

// ---------------- fused attn single-pass: LDS-staged K/V, per-2kt flush of normalized attn, PV ----
__global__ __launch_bounds__(256) void attnpv_kernel(
    const u16* __restrict__ Qh, const u16* __restrict__ Kh, const u16* __restrict__ Vt,
    const u64* __restrict__ bits, const float* __restrict__ invs,
    float* __restrict__ attn, u16* __restrict__ heads)
{
    const int j   = blockIdx.x;
    const int lid = (j & 7) * 128 + (j >> 3);     // XCD-contiguous bh ranges
    const int qt = lid & 31, bh = lid >> 5;
    const int b = bh >> 3, h = bh & 7;
    const int m0 = qt * 64;
    const int t = threadIdx.x, l = t & 63, w = t >> 6;
    const int q = l & 15, G = l >> 4;
    const int qrow = m0 + w*16 + q;
    __shared__ u16 kbuf[2][4096];          // 64x64 bf16 K tile (16KB)
    __shared__ u16 vbuf[2][4096];          // 64x64 bf16 V^T tile (16KB)
    __shared__ u16 alds2[4][2048];         // per-wave 2x(16x64) E tiles (16KB)
    __shared__ float sinv[64];
    u16* alds2w = alds2[w];

    const size_t qbase = (((size_t)bh << 11) + qrow) * 64;
    bf16x8 qf0 = *(const bf16x8*)(Qh + qbase + G*8);
    bf16x8 qf1 = *(const bf16x8*)(Qh + qbase + 32 + G*8);
    const u64* brow = bits + (((size_t)b << 11) + qrow) * 32;
    const int swz = (q & 7) << 3;
    const float inv = invs[((size_t)bh << 11) + qrow];
    if (G == 0) sinv[w*16 + q] = inv;

    const int srow0 = t >> 3;
    const int scol  = (t & 7) * 8;
    const u16* Kbase = Kh + (((size_t)bh << 11) * 64);
    const u16* Vbase = Vt + (((size_t)bh << 6) * 2048);
    const int eswz = (t * 8) ^ ((srow0 & 7) << 3);

    bf16x8 sk0, sk1, sv0, sv1;
    f32x4 pacc[4] = {};

    {
        const u16* kp = Kbase + (size_t)srow0 * 64 + scol;
        sk0 = *(const bf16x8*)kp;
        sk1 = *(const bf16x8*)(kp + 32 * 64);
        const u16* vp = Vbase + (size_t)srow0 * 2048 + scol;
        sv0 = *(const bf16x8*)vp;
        sv1 = *(const bf16x8*)(vp + 32 * 2048);
        *(bf16x8*)&kbuf[0][eswz]        = sk0;
        *(bf16x8*)&kbuf[0][2048 + eswz] = sk1;
        *(bf16x8*)&vbuf[0][eswz]        = sv0;
        *(bf16x8*)&vbuf[0][2048 + eswz] = sv1;
    }
    __syncthreads();
    for (int kt = 0; kt < 32; ++kt) {
        const int cur = kt & 1;
        if (kt < 31) {
            const int n1 = (kt + 1) * 64;
            const u16* kp = Kbase + (size_t)(n1 + srow0) * 64 + scol;
            sk0 = *(const bf16x8*)kp;
            sk1 = *(const bf16x8*)(kp + 32 * 64);
            const u16* vp = Vbase + (size_t)srow0 * 2048 + n1 + scol;
            sv0 = *(const bf16x8*)vp;
            sv1 = *(const bf16x8*)(vp + 32 * 2048);
        }
        f32x4 acc[4] = {};
        #pragma unroll
        for (int mt = 0; mt < 4; ++mt) {
            const int r = mt*16 + q;
            const int rsw = (r & 7) << 3;
            bf16x8 k0 = *(const bf16x8*)&kbuf[cur][(r*64 +      G*8) ^ rsw];
            bf16x8 k1 = *(const bf16x8*)&kbuf[cur][(r*64 + 32 + G*8) ^ rsw];
            acc[mt] = MFMA16(k0, qf0, acc[mt], 0, 0, 0);
            acc[mt] = MFMA16(k1, qf1, acc[mt], 0, 0, 0);
        }
        const u64 mw = brow[kt];
        u16* A2 = alds2w + (kt & 1) * 1024;
        #pragma unroll
        for (int mt = 0; mt < 4; ++mt) {
            short4v sv;
            #pragma unroll
            for (int r = 0; r < 4; ++r) {
                const int c = mt*16 + G*4 + r;
                const float e = ((mw >> c) & 1) ? 0.f : exp2f(acc[mt][r] * L2E);
                sv[r] = (short)f2bf(e);
            }
            *(short4v*)&A2[(q*64 + mt*16 + G*4) ^ swz] = sv;
        }
        bf16x8 an0 = *(const bf16x8*)&A2[(q*64 +  0 + G*8) ^ swz];
        bf16x8 an1 = *(const bf16x8*)&A2[(q*64 + 32 + G*8) ^ swz];
        #pragma unroll
        for (int dmt = 0; dmt < 4; ++dmt) {
            const int r = dmt*16 + q;
            const int rsw = (r & 7) << 3;
            bf16x8 v0 = *(const bf16x8*)&vbuf[cur][(r*64 +      G*8) ^ rsw];
            bf16x8 v1 = *(const bf16x8*)&vbuf[cur][(r*64 + 32 + G*8) ^ rsw];
            pacc[dmt] = MFMA16(v0, an0, pacc[dmt], 0, 0, 0);
            pacc[dmt] = MFMA16(v1, an1, pacc[dmt], 0, 0, 0);
        }
        if (kt < 31) {
            const int nxt = cur ^ 1;
            *(bf16x8*)&kbuf[nxt][eswz]        = sk0;
            *(bf16x8*)&kbuf[nxt][2048 + eswz] = sk1;
            *(bf16x8*)&vbuf[nxt][eswz]        = sv0;
            *(bf16x8*)&vbuf[nxt][2048 + eswz] = sv1;
        }
        if (kt & 1) {
            // flush 2 staged kt tiles: per row, wave writes 512B contiguous (128 keys f32)
            const int ktg = kt >> 1;                 // 0..15
            const u16* A2f = alds2w + (l >> 5) * 1024;
            float* awbase = attn + ((((size_t)bh << 11) + m0 + w*16) << 11) + ktg*128 + l*2;
            #pragma unroll
            for (int r = 0; r < 16; ++r) {
                const float iv = sinv[w*16 + r];
                const u32 e2 = *(const u32*)&A2f[(r*64 + (l & 31)*2) ^ ((r & 7) << 3)];
                f32x2 o;
                o[0] = bf2f((u16)(e2 & 0xffffu)) * iv;
                o[1] = bf2f((u16)(e2 >> 16))     * iv;
                *(f32x2*)(awbase + (size_t)r * 2048) = o;
            }
        }
        __syncthreads();
    }
    #pragma unroll
    for (int dmt = 0; dmt < 4; ++dmt) {
        short4v sv;
        #pragma unroll
        for (int r = 0; r < 4; ++r) sv[r] = (short)f2bf(pacc[dmt][r] * inv);
        *(short4v*)&heads[(((size_t)b << 11) + qrow) * 512 + h*64 + dmt*16 + G*4] = sv;
    }
}

// ---------------- K4: out = heads(bf16) @ wo + q residual ----------------
__global__ __launch_bounds__(256) void outgemm_kernel(
    const u16* __restrict__ heads, const u16* __restrict__ wt,
    const float* __restrict__ qin, float* __restrict__ out)
{
    const int m0 = blockIdx.x * 64, n0b = blockIdx.y * 64;
    const int t = threadIdx.x, l = t & 63, w = t >> 6;
    const int q = l & 15, G = l >> 4;
    const int wr = w >> 1, wc = w & 1;
    const u16* W = wt + (size_t)3 * 512 * 512;
    f32x4 acc[2][2] = {};
    for (int k0 = 0; k0 < 512; k0 += 32) {
        bf16x8 af[2], bfr[2];
        #pragma unroll
        for (int mi = 0; mi < 2; ++mi)
            af[mi] = *(const bf16x8*)(heads + (size_t)(m0 + wr*32 + mi*16 + q) * 512 + k0 + G*8);
        #pragma unroll
        for (int tn = 0; tn < 2; ++tn)
            bfr[tn] = *(const bf16x8*)(W + (size_t)(n0b + wc*32 + tn*16 + q) * 512 + k0 + G*8);
        #pragma unroll
        for (int mi = 0; mi < 2; ++mi)
            #pragma unroll
            for (int tn = 0; tn < 2; ++tn)
                acc[mi][tn] = MFMA16(af[mi], bfr[tn], acc[mi][tn], 0, 0, 0);
    }
    #pragma unroll
    for (int mi = 0; mi < 2; ++mi)
        #pragma unroll
        for (int r = 0; r < 4; ++r) {
            const int m = m0 + wr*32 + mi*16 + G*4 + r;
            #pragma unroll
            for (int tn = 0; tn < 2; ++tn) {
                const int n = n0b + wc*32 + tn*16 + q;
                out[(size_t)m * 512 + n] = acc[mi][tn][r] + qin[(size_t)m * 512 + n];
            }
        }
}

// ---------------- K5: in-place row LayerNorm ----------------
__global__ __launch_bounds__(256) void ln_kernel(
    float* __restrict__ out, const float* __restrict__ g, const float* __restrict__ be)
{
    const int m = blockIdx.x;
    float* row = out + (size_t)m * 512;
    const int t = threadIdx.x;
    float2 v = ((const float2*)row)[t];
    float s  = block_sum256(v.x + v.y);
    float s2 = block_sum256(v.x * v.x + v.y * v.y);
    const float mu  = s * (1.0f / 512.0f);
    const float var = s2 * (1.0f / 512.0f) - mu * mu;
    const float inv = rsqrtf(var + LN_EPS);
    float2 gg = ((const float2*)g)[t];
    float2 bb = ((const float2*)be)[t];
    float2 r;
    r.x = (v.x - mu) * inv * gg.x + bb.x;
    r.y = (v.y - mu) * inv * gg.y + bb.y;
    ((float2*)row)[t] = r;
}

// ---------------- launch ----------------
extern "C" void kernel_launch(void* const* d_in, const int* in_sizes, int n_in,
                              void* d_out, int out_size, void* d_ws, size_t ws_size,
                              hipStream_t stream) {
    const float* q   = (const float*)d_in[0];
    const float* k   = (const float*)d_in[1];
    const float* v   = (const float*)d_in[2];
    const float* wq  = (const float*)d_in[3];
    const float* wk  = (const float*)d_in[4];
    const float* wv  = (const float*)d_in[5];
    const float* wo  = (const float*)d_in[6];
    const float* g   = (const float*)d_in[7];
    const float* be  = (const float*)d_in[8];
    const int*   msk = (const int*)d_in[9];

    float* out  = (float*)d_out;
    float* attn = out + (size_t)4 * 2048 * 512;

    const size_t nQKV = (size_t)32 * 2048 * 64;          // 4M u16 per tensor
    u16* Qh    = (u16*)d_ws;
    u16* Kh    = Qh + nQKV;
    u16* Vt    = Kh + nQKV;
    u16* heads = Vt + nQKV;
    u16* wt    = heads + (size_t)8192 * 512;
    u64* bits  = (u64*)(wt + (size_t)4 * 512 * 512);
    float* invs = (float*)(bits + (size_t)8192 * 32);    // 65536 f32

    prepw_kernel  <<<dim3(8, 8, 4),    256, 0, stream>>>(wq, wk, wv, wo, wt);
    proj_kernel   <<<dim3(128, 8, 3),  256, 0, stream>>>(q, k, v, wt, Qh, Kh, Vt);
    maskrow_kernel<<<dim3(128, 4),     256, 0, stream>>>(msk, Qh, Kh, bits, invs);
    attnpv_kernel <<<dim3(1024),       256, 0, stream>>>(Qh, Kh, Vt, bits, invs, attn, heads);
    outgemm_kernel<<<dim3(128, 8),     256, 0, stream>>>(heads, wt, q, out);
    ln_kernel     <<<dim3(8192),       256, 0, stream>>>(out, g, be);
}

// Round 16
// 447.523 us; speedup vs baseline: 1.2416x; 1.2416x over previous
//
#include <hip/hip_runtime.h>
#include <cstddef>

typedef __attribute__((ext_vector_type(8))) short bf16x8;
typedef __attribute__((ext_vector_type(4))) float f32x4;
typedef __attribute__((ext_vector_type(2))) float f32x2;
typedef __attribute__((ext_vector_type(4))) short short4v;
typedef unsigned long long u64;
typedef unsigned int u32;
typedef unsigned short u16;

#define MFMA16 __builtin_amdgcn_mfma_f32_16x16x32_bf16
static constexpr float LN_EPS = 1e-5f;
static constexpr float L2E = 1.44269504f;

__device__ __forceinline__ u16 f2bf(float f) {
    u32 u = __builtin_bit_cast(u32, f);
    return (u16)((u + 0x7FFFu + ((u >> 16) & 1u)) >> 16);
}
__device__ __forceinline__ float bf2f(u16 h) {
    u32 u = ((u32)h) << 16;
    return __builtin_bit_cast(float, u);
}

// ---------------- block-wide sum (256 threads) ----------------
__device__ __forceinline__ float block_sum256(float v) {
    __shared__ float sc[4];
    #pragma unroll
    for (int o = 32; o > 0; o >>= 1) v += __shfl_down(v, o);
    if ((threadIdx.x & 63) == 0) sc[threadIdx.x >> 6] = v;
    __syncthreads();
    v = sc[0] + sc[1] + sc[2] + sc[3];
    __syncthreads();
    return v;
}

// ---------------- prep: weights fp32 [k][n] -> bf16 Wt [mat][n][k] ----------------
__global__ __launch_bounds__(256) void prepw_kernel(
    const float* __restrict__ wq, const float* __restrict__ wk,
    const float* __restrict__ wv, const float* __restrict__ wo,
    u16* __restrict__ wt)
{
    const int mat = blockIdx.z;
    const float* W = mat == 0 ? wq : mat == 1 ? wk : mat == 2 ? wv : wo;
    const int k0 = blockIdx.x * 64, n0 = blockIdx.y * 64;
    __shared__ u16 ld[64][72];
    const int t = threadIdx.x;
    {
        const int kk = t >> 2;
        #pragma unroll
        for (int j = 0; j < 4; ++j) {
            const int nn = ((t & 3) + j * 4) * 4;
            float4 x = *(const float4*)&W[(size_t)(k0 + kk) * 512 + n0 + nn];
            ld[kk][nn + 0] = f2bf(x.x); ld[kk][nn + 1] = f2bf(x.y);
            ld[kk][nn + 2] = f2bf(x.z); ld[kk][nn + 3] = f2bf(x.w);
        }
    }
    __syncthreads();
    {
        const int n = t & 63, kc = (t >> 6) * 16;
        u16* op = wt + ((size_t)mat * 512 + n0 + n) * 512 + k0 + kc;
        #pragma unroll
        for (int j = 0; j < 4; ++j) {
            short4v v;
            v[0] = ld[kc + j*4 + 0][n]; v[1] = ld[kc + j*4 + 1][n];
            v[2] = ld[kc + j*4 + 2][n]; v[3] = ld[kc + j*4 + 3][n];
            *(short4v*)(op + j * 4) = v;
        }
    }
}

// ---------------- prep: mask int32 -> bit-packed u64 [8192 rows][32 words] ----------------
__global__ __launch_bounds__(256) void prepm_kernel(
    const int* __restrict__ mask, u64* __restrict__ bits)
{
    const int t = threadIdx.x;
    const int row = blockIdx.x * 4 + (t >> 6);
    const int wl = t & 63;
    const int* mrow = mask + (size_t)row * 2048;
    u64* brow = bits + (size_t)row * 32;
    #pragma unroll 8
    for (int it = 0; it < 32; ++it) {
        u64 b = __ballot(mrow[it * 64 + wl] != 0);
        if (wl == 0) brow[it] = b;
    }
}

// ---------------- K1: projections via MFMA. X fp32 @ Wt -> Qh/Kh bf16 [bh][s][64], V -> Vt [bh][64][2048]
__global__ __launch_bounds__(256) void proj_kernel(
    const float* __restrict__ qin, const float* __restrict__ kin, const float* __restrict__ vin,
    const u16* __restrict__ wt,
    u16* __restrict__ Qh, u16* __restrict__ Kh, u16* __restrict__ Vt)
{
    const int z = blockIdx.z;
    const float* X = z == 0 ? qin : (z == 1 ? kin : vin);
    const u16* W = wt + (size_t)z * 512 * 512;
    const int m0 = blockIdx.x * 64;
    const int h = blockIdx.y;
    const int t = threadIdx.x, l = t & 63, w = t >> 6;
    const int q = l & 15, G = l >> 4;
    const int wr = w >> 1, wc = w & 1;

    f32x4 acc[2][2] = {};
    for (int k0 = 0; k0 < 512; k0 += 32) {
        bf16x8 af[2], bfr[2];
        #pragma unroll
        for (int mi = 0; mi < 2; ++mi) {
            const float* xp = X + (size_t)(m0 + wr*32 + mi*16 + q) * 512 + k0 + G*8;
            float4 x0 = *(const float4*)xp;
            float4 x1 = *(const float4*)(xp + 4);
            bf16x8 a;
            a[0] = f2bf(x0.x); a[1] = f2bf(x0.y); a[2] = f2bf(x0.z); a[3] = f2bf(x0.w);
            a[4] = f2bf(x1.x); a[5] = f2bf(x1.y); a[6] = f2bf(x1.z); a[7] = f2bf(x1.w);
            af[mi] = a;
        }
        #pragma unroll
        for (int tn = 0; tn < 2; ++tn)
            bfr[tn] = *(const bf16x8*)(W + (size_t)(h*64 + wc*32 + tn*16 + q) * 512 + k0 + G*8);
        #pragma unroll
        for (int mi = 0; mi < 2; ++mi)
            #pragma unroll
            for (int tn = 0; tn < 2; ++tn)
                acc[mi][tn] = MFMA16(af[mi], bfr[tn], acc[mi][tn], 0, 0, 0);
    }
    if (z == 2) {
        // V: write transposed directly -> Vt[bh][d][s], 4 consecutive s per lane (8B)
        #pragma unroll
        for (int mi = 0; mi < 2; ++mi)
            #pragma unroll
            for (int tn = 0; tn < 2; ++tn) {
                const int d = wc*32 + tn*16 + q;
                const int m = m0 + wr*32 + mi*16 + G*4;
                const int bb = m >> 11, s = m & 2047;
                short4v sv;
                #pragma unroll
                for (int r = 0; r < 4; ++r) sv[r] = (short)f2bf(acc[mi][tn][r]);
                *(short4v*)&Vt[(((size_t)(bb*8 + h) << 6) + d) * 2048 + s] = sv;
            }
    } else {
        u16* O = z == 0 ? Qh : Kh;
        const float scv = (z == 0) ? 0.125f : 1.0f;   // fold 1/sqrt(64) into Q (exact pow2)
        #pragma unroll
        for (int mi = 0; mi < 2; ++mi)
            #pragma unroll
            for (int tn = 0; tn < 2; ++tn)
                #pragma unroll
                for (int r = 0; r < 4; ++r) {
                    const int m = m0 + wr*32 + mi*16 + G*4 + r;
                    const int bb = m >> 11, s = m & 2047;
                    const int d = wc*32 + tn*16 + q;
                    O[(((size_t)(bb*8 + h) << 11) + s) * 64 + d] = f2bf(acc[mi][tn][r] * scv);
                }
    }
}

// ---------------- fused attn, two-phase, qt-PAIRED (2 Q-tiles per block):
// grid 512 (all resident, zero tail). Each staged K/V tile feeds both Q-tiles
// (2x MFMA per barrier/staging byte). Per-kt flush, 256B bursts.
__global__ __launch_bounds__(256) void attnpv_kernel(
    const u16* __restrict__ Qh, const u16* __restrict__ Kh, const u16* __restrict__ Vt,
    const u64* __restrict__ bits,
    float* __restrict__ attn, u16* __restrict__ heads)
{
    const int j   = blockIdx.x;                 // 0..511
    const int lid = (j & 7) * 64 + (j >> 3);    // XCD-contiguous: 4 bh per XCD
    const int qt = lid & 15, bh = lid >> 4;
    const int b = bh >> 3, h = bh & 7;
    const int m0A = qt * 64, m0B = (qt + 16) * 64;
    const int t = threadIdx.x, l = t & 63, w = t >> 6;
    const int q = l & 15, G = l >> 4;
    const int qrowA = m0A + w*16 + q, qrowB = m0B + w*16 + q;
    __shared__ u16 kbuf[2][4096];          // 64x64 bf16 K tile (16KB)
    __shared__ u16 vbuf[2][4096];          // 64x64 bf16 V^T tile (16KB)
    __shared__ u16 alds[4][2048];          // per-wave: [0..1023] qtA E tile, [1024..] qtB (16KB)
    __shared__ float sinv[2][64];
    u16* myA = alds[w];
    u16* myB = alds[w] + 1024;

    const size_t qbaseA = (((size_t)bh << 11) + qrowA) * 64;
    const size_t qbaseB = (((size_t)bh << 11) + qrowB) * 64;
    bf16x8 qfA0 = *(const bf16x8*)(Qh + qbaseA + G*8);
    bf16x8 qfA1 = *(const bf16x8*)(Qh + qbaseA + 32 + G*8);
    bf16x8 qfB0 = *(const bf16x8*)(Qh + qbaseB + G*8);
    bf16x8 qfB1 = *(const bf16x8*)(Qh + qbaseB + 32 + G*8);
    const u64* browA = bits + (((size_t)b << 11) + qrowA) * 32;
    const u64* browB = bits + (((size_t)b << 11) + qrowB) * 32;
    const int swz = (q & 7) << 3;

    // staging geometry: thread covers rows srow0 (i=0) and srow0+32 (i=1), 16B each
    const int srow0 = t >> 3;
    const int scol  = (t & 7) * 8;
    const u16* Kbase = Kh + (((size_t)bh << 11) * 64);
    const u16* Vbase = Vt + (((size_t)bh << 6) * 2048);
    const int eswz = (t * 8) ^ ((srow0 & 7) << 3);

    bf16x8 sk0, sk1, sv0, sv1;
    float rsA = 0.f, rsB = 0.f;

    // ======== phase 1: row sums (K only), both q-tiles per staged tile ========
    {
        const u16* kp = Kbase + (size_t)srow0 * 64 + scol;
        sk0 = *(const bf16x8*)kp;
        sk1 = *(const bf16x8*)(kp + 32 * 64);
        *(bf16x8*)&kbuf[0][eswz]        = sk0;
        *(bf16x8*)&kbuf[0][2048 + eswz] = sk1;
    }
    __syncthreads();
    for (int kt = 0; kt < 32; ++kt) {
        const int cur = kt & 1;
        if (kt < 31) {
            const u16* kp = Kbase + (size_t)((kt + 1) * 64 + srow0) * 64 + scol;
            sk0 = *(const bf16x8*)kp;
            sk1 = *(const bf16x8*)(kp + 32 * 64);
        }
        f32x4 accA[4] = {}, accB[4] = {};
        #pragma unroll
        for (int mt = 0; mt < 4; ++mt) {
            const int r = mt*16 + q;
            const int rsw = (r & 7) << 3;
            bf16x8 k0 = *(const bf16x8*)&kbuf[cur][(r*64 +      G*8) ^ rsw];
            bf16x8 k1 = *(const bf16x8*)&kbuf[cur][(r*64 + 32 + G*8) ^ rsw];
            accA[mt] = MFMA16(k0, qfA0, accA[mt], 0, 0, 0);
            accA[mt] = MFMA16(k1, qfA1, accA[mt], 0, 0, 0);
            accB[mt] = MFMA16(k0, qfB0, accB[mt], 0, 0, 0);
            accB[mt] = MFMA16(k1, qfB1, accB[mt], 0, 0, 0);
        }
        const u64 mwA = browA[kt];
        const u64 mwB = browB[kt];
        #pragma unroll
        for (int mt = 0; mt < 4; ++mt)
            #pragma unroll
            for (int r = 0; r < 4; ++r) {
                const int c = mt*16 + G*4 + r;
                rsA += ((mwA >> c) & 1) ? 0.f : exp2f(accA[mt][r] * L2E);
                rsB += ((mwB >> c) & 1) ? 0.f : exp2f(accB[mt][r] * L2E);
            }
        if (kt < 31) {
            *(bf16x8*)&kbuf[cur ^ 1][eswz]        = sk0;
            *(bf16x8*)&kbuf[cur ^ 1][2048 + eswz] = sk1;
        }
        __syncthreads();
    }
    rsA += __shfl_xor(rsA, 16);
    rsA += __shfl_xor(rsA, 32);
    rsB += __shfl_xor(rsB, 16);
    rsB += __shfl_xor(rsB, 32);
    const float invA = 1.0f / rsA;
    const float invB = 1.0f / rsB;
    if (G == 0) { sinv[0][w*16 + q] = invA; sinv[1][w*16 + q] = invB; }

    // ======== phase 2: recompute QK (both tiles), per-kt flush, PV ========
    f32x4 paccA[4] = {}, paccB[4] = {};
    {
        const u16* kp = Kbase + (size_t)srow0 * 64 + scol;
        sk0 = *(const bf16x8*)kp;
        sk1 = *(const bf16x8*)(kp + 32 * 64);
        const u16* vp = Vbase + (size_t)srow0 * 2048 + scol;
        sv0 = *(const bf16x8*)vp;
        sv1 = *(const bf16x8*)(vp + 32 * 2048);
        *(bf16x8*)&kbuf[0][eswz]        = sk0;
        *(bf16x8*)&kbuf[0][2048 + eswz] = sk1;
        *(bf16x8*)&vbuf[0][eswz]        = sv0;
        *(bf16x8*)&vbuf[0][2048 + eswz] = sv1;
    }
    __syncthreads();      // also publishes sinv
    for (int kt = 0; kt < 32; ++kt) {
        const int cur = kt & 1;
        if (kt < 31) {
            const int n1 = (kt + 1) * 64;
            const u16* kp = Kbase + (size_t)(n1 + srow0) * 64 + scol;
            sk0 = *(const bf16x8*)kp;
            sk1 = *(const bf16x8*)(kp + 32 * 64);
            const u16* vp = Vbase + (size_t)srow0 * 2048 + n1 + scol;
            sv0 = *(const bf16x8*)vp;
            sv1 = *(const bf16x8*)(vp + 32 * 2048);
        }
        // ---- q-tile A: QK, E tile ----
        {
            f32x4 acc[4] = {};
            #pragma unroll
            for (int mt = 0; mt < 4; ++mt) {
                const int r = mt*16 + q;
                const int rsw = (r & 7) << 3;
                bf16x8 k0 = *(const bf16x8*)&kbuf[cur][(r*64 +      G*8) ^ rsw];
                bf16x8 k1 = *(const bf16x8*)&kbuf[cur][(r*64 + 32 + G*8) ^ rsw];
                acc[mt] = MFMA16(k0, qfA0, acc[mt], 0, 0, 0);
                acc[mt] = MFMA16(k1, qfA1, acc[mt], 0, 0, 0);
            }
            const u64 mw = browA[kt];
            #pragma unroll
            for (int mt = 0; mt < 4; ++mt) {
                short4v sv;
                #pragma unroll
                for (int r = 0; r < 4; ++r) {
                    const int c = mt*16 + G*4 + r;
                    const float e = ((mw >> c) & 1) ? 0.f : exp2f(acc[mt][r] * L2E);
                    sv[r] = (short)f2bf(e);
                }
                *(short4v*)&myA[(q*64 + mt*16 + G*4) ^ swz] = sv;
            }
        }
        // ---- q-tile B: QK, E tile ----
        {
            f32x4 acc[4] = {};
            #pragma unroll
            for (int mt = 0; mt < 4; ++mt) {
                const int r = mt*16 + q;
                const int rsw = (r & 7) << 3;
                bf16x8 k0 = *(const bf16x8*)&kbuf[cur][(r*64 +      G*8) ^ rsw];
                bf16x8 k1 = *(const bf16x8*)&kbuf[cur][(r*64 + 32 + G*8) ^ rsw];
                acc[mt] = MFMA16(k0, qfB0, acc[mt], 0, 0, 0);
                acc[mt] = MFMA16(k1, qfB1, acc[mt], 0, 0, 0);
            }
            const u64 mw = browB[kt];
            #pragma unroll
            for (int mt = 0; mt < 4; ++mt) {
                short4v sv;
                #pragma unroll
                for (int r = 0; r < 4; ++r) {
                    const int c = mt*16 + G*4 + r;
                    const float e = ((mw >> c) & 1) ? 0.f : exp2f(acc[mt][r] * L2E);
                    sv[r] = (short)f2bf(e);
                }
                *(short4v*)&myB[(q*64 + mt*16 + G*4) ^ swz] = sv;
            }
        }
        // ---- PV for both tiles (V frags read once) ----
        bf16x8 anA0 = *(const bf16x8*)&myA[(q*64 +  0 + G*8) ^ swz];
        bf16x8 anA1 = *(const bf16x8*)&myA[(q*64 + 32 + G*8) ^ swz];
        bf16x8 anB0 = *(const bf16x8*)&myB[(q*64 +  0 + G*8) ^ swz];
        bf16x8 anB1 = *(const bf16x8*)&myB[(q*64 + 32 + G*8) ^ swz];
        #pragma unroll
        for (int dmt = 0; dmt < 4; ++dmt) {
            const int r = dmt*16 + q;
            const int rsw = (r & 7) << 3;
            bf16x8 v0 = *(const bf16x8*)&vbuf[cur][(r*64 +      G*8) ^ rsw];
            bf16x8 v1 = *(const bf16x8*)&vbuf[cur][(r*64 + 32 + G*8) ^ rsw];
            paccA[dmt] = MFMA16(v0, anA0, paccA[dmt], 0, 0, 0);
            paccA[dmt] = MFMA16(v1, anA1, paccA[dmt], 0, 0, 0);
            paccB[dmt] = MFMA16(v0, anB0, paccB[dmt], 0, 0, 0);
            paccB[dmt] = MFMA16(v1, anB1, paccB[dmt], 0, 0, 0);
        }
        if (kt < 31) {
            const int nxt = cur ^ 1;
            *(bf16x8*)&kbuf[nxt][eswz]        = sk0;
            *(bf16x8*)&kbuf[nxt][2048 + eswz] = sk1;
            *(bf16x8*)&vbuf[nxt][eswz]        = sv0;
            *(bf16x8*)&vbuf[nxt][2048 + eswz] = sv1;
        }
        // ---- flush both tiles for this kt: half-wave row split, f32x2/lane,
        //      two 256B segments per store instruction ----
        {
            const int rr = l >> 5;              // 0 or 1
            const int cc = (l & 31) * 2;
            float* awA = attn + ((((size_t)bh << 11) + m0A + w*16) << 11) + kt*64 + cc;
            float* awB = attn + ((((size_t)bh << 11) + m0B + w*16) << 11) + kt*64 + cc;
            #pragma unroll
            for (int it = 0; it < 8; ++it) {
                const int r = it*2 + rr;
                const int off = (r*64 + cc) ^ ((r & 7) << 3);
                const u32 eA = *(const u32*)&myA[off];
                const u32 eB = *(const u32*)&myB[off];
                const float ivA = sinv[0][w*16 + r];
                const float ivB = sinv[1][w*16 + r];
                f32x2 oA, oB;
                oA[0] = bf2f((u16)(eA & 0xffffu)) * ivA;
                oA[1] = bf2f((u16)(eA >> 16))     * ivA;
                oB[0] = bf2f((u16)(eB & 0xffffu)) * ivB;
                oB[1] = bf2f((u16)(eB >> 16))     * ivB;
                *(f32x2*)(awA + (size_t)r * 2048) = oA;
                *(f32x2*)(awB + (size_t)r * 2048) = oB;
            }
        }
        __syncthreads();
    }
    #pragma unroll
    for (int dmt = 0; dmt < 4; ++dmt) {
        short4v svA, svB;
        #pragma unroll
        for (int r = 0; r < 4; ++r) {
            svA[r] = (short)f2bf(paccA[dmt][r] * invA);
            svB[r] = (short)f2bf(paccB[dmt][r] * invB);
        }
        *(short4v*)&heads[(((size_t)b << 11) + qrowA) * 512 + h*64 + dmt*16 + G*4] = svA;
        *(short4v*)&heads[(((size_t)b << 11) + qrowB) * 512 + h*64 + dmt*16 + G*4] = svB;
    }
}

// ---------------- K4: out = heads(bf16) @ wo + q residual ----------------
__global__ __launch_bounds__(256) void outgemm_kernel(
    const u16* __restrict__ heads, const u16* __restrict__ wt,
    const float* __restrict__ qin, float* __restrict__ out)
{
    const int m0 = blockIdx.x * 64, n0b = blockIdx.y * 64;
    const int t = threadIdx.x, l = t & 63, w = t >> 6;
    const int q = l & 15, G = l >> 4;
    const int wr = w >> 1, wc = w & 1;
    const u16* W = wt + (size_t)3 * 512 * 512;
    f32x4 acc[2][2] = {};
    for (int k0 = 0; k0 < 512; k0 += 32) {
        bf16x8 af[2], bfr[2];
        #pragma unroll
        for (int mi = 0; mi < 2; ++mi)
            af[mi] = *(const bf16x8*)(heads + (size_t)(m0 + wr*32 + mi*16 + q) * 512 + k0 + G*8);
        #pragma unroll
        for (int tn = 0; tn < 2; ++tn)
            bfr[tn] = *(const bf16x8*)(W + (size_t)(n0b + wc*32 + tn*16 + q) * 512 + k0 + G*8);
        #pragma unroll
        for (int mi = 0; mi < 2; ++mi)
            #pragma unroll
            for (int tn = 0; tn < 2; ++tn)
                acc[mi][tn] = MFMA16(af[mi], bfr[tn], acc[mi][tn], 0, 0, 0);
    }
    #pragma unroll
    for (int mi = 0; mi < 2; ++mi)
        #pragma unroll
        for (int r = 0; r < 4; ++r) {
            const int m = m0 + wr*32 + mi*16 + G*4 + r;
            #pragma unroll
            for (int tn = 0; tn < 2; ++tn) {
                const int n = n0b + wc*32 + tn*16 + q;
                out[(size_t)m * 512 + n] = acc[mi][tn][r] + qin[(size_t)m * 512 + n];
            }
        }
}

// ---------------- K5: in-place row LayerNorm ----------------
__global__ __launch_bounds__(256) void ln_kernel(
    float* __restrict__ out, const float* __restrict__ g, const float* __restrict__ be)
{
    const int m = blockIdx.x;
    float* row = out + (size_t)m * 512;
    const int t = threadIdx.x;
    float2 v = ((const float2*)row)[t];
    float s  = block_sum256(v.x + v.y);
    float s2 = block_sum256(v.x * v.x + v.y * v.y);
    const float mu  = s * (1.0f / 512.0f);
    const float var = s2 * (1.0f / 512.0f) - mu * mu;
    const float inv = rsqrtf(var + LN_EPS);
    float2 gg = ((const float2*)g)[t];
    float2 bb = ((const float2*)be)[t];
    float2 r;
    r.x = (v.x - mu) * inv * gg.x + bb.x;
    r.y = (v.y - mu) * inv * gg.y + bb.y;
    ((float2*)row)[t] = r;
}

// ---------------- launch ----------------
extern "C" void kernel_launch(void* const* d_in, const int* in_sizes, int n_in,
                              void* d_out, int out_size, void* d_ws, size_t ws_size,
                              hipStream_t stream) {
    const float* q   = (const float*)d_in[0];
    const float* k   = (const float*)d_in[1];
    const float* v   = (const float*)d_in[2];
    const float* wq  = (const float*)d_in[3];
    const float* wk  = (const float*)d_in[4];
    const float* wv  = (const float*)d_in[5];
    const float* wo  = (const float*)d_in[6];
    const float* g   = (const float*)d_in[7];
    const float* be  = (const float*)d_in[8];
    const int*   msk = (const int*)d_in[9];

    float* out  = (float*)d_out;
    float* attn = out + (size_t)4 * 2048 * 512;

    const size_t nQKV = (size_t)32 * 2048 * 64;          // 4M u16 per tensor
    u16* Qh    = (u16*)d_ws;
    u16* Kh    = Qh + nQKV;
    u16* Vt    = Kh + nQKV;
    u16* heads = Vt + nQKV;
    u16* wt    = heads + (size_t)8192 * 512;
    u64* bits  = (u64*)(wt + (size_t)4 * 512 * 512);

    prepw_kernel  <<<dim3(8, 8, 4),    256, 0, stream>>>(wq, wk, wv, wo, wt);
    prepm_kernel  <<<dim3(2048),       256, 0, stream>>>(msk, bits);
    proj_kernel   <<<dim3(128, 8, 3),  256, 0, stream>>>(q, k, v, wt, Qh, Kh, Vt);
    attnpv_kernel <<<dim3(512),        256, 0, stream>>>(Qh, Kh, Vt, bits, attn, heads);
    outgemm_kernel<<<dim3(128, 8),     256, 0, stream>>>(heads, wt, q, out);
    ln_kernel     <<<dim3(8192),       256, 0, stream>>>(out, g, be);
}

// Round 17
// 442.585 us; speedup vs baseline: 1.2554x; 1.0112x over previous
//
#include <hip/hip_runtime.h>
#include <cstddef>

typedef __attribute__((ext_vector_type(8))) short bf16x8;
typedef __attribute__((ext_vector_type(4))) float f32x4;
typedef __attribute__((ext_vector_type(2))) float f32x2;
typedef __attribute__((ext_vector_type(4))) short short4v;
typedef unsigned long long u64;
typedef unsigned int u32;
typedef unsigned short u16;

#define MFMA16 __builtin_amdgcn_mfma_f32_16x16x32_bf16
static constexpr float LN_EPS = 1e-5f;
static constexpr float L2E = 1.44269504f;

__device__ __forceinline__ u16 f2bf(float f) {
    u32 u = __builtin_bit_cast(u32, f);
    return (u16)((u + 0x7FFFu + ((u >> 16) & 1u)) >> 16);
}
__device__ __forceinline__ float bf2f(u16 h) {
    u32 u = ((u32)h) << 16;
    return __builtin_bit_cast(float, u);
}

// ---------------- block-wide sum (256 threads) ----------------
__device__ __forceinline__ float block_sum256(float v) {
    __shared__ float sc[4];
    #pragma unroll
    for (int o = 32; o > 0; o >>= 1) v += __shfl_down(v, o);
    if ((threadIdx.x & 63) == 0) sc[threadIdx.x >> 6] = v;
    __syncthreads();
    v = sc[0] + sc[1] + sc[2] + sc[3];
    __syncthreads();
    return v;
}

// ---------------- prep: weights fp32 [k][n] -> bf16 Wt [mat][n][k] ----------------
__global__ __launch_bounds__(256) void prepw_kernel(
    const float* __restrict__ wq, const float* __restrict__ wk,
    const float* __restrict__ wv, const float* __restrict__ wo,
    u16* __restrict__ wt)
{
    const int mat = blockIdx.z;
    const float* W = mat == 0 ? wq : mat == 1 ? wk : mat == 2 ? wv : wo;
    const int k0 = blockIdx.x * 64, n0 = blockIdx.y * 64;
    __shared__ u16 ld[64][72];
    const int t = threadIdx.x;
    {
        const int kk = t >> 2;
        #pragma unroll
        for (int j = 0; j < 4; ++j) {
            const int nn = ((t & 3) + j * 4) * 4;
            float4 x = *(const float4*)&W[(size_t)(k0 + kk) * 512 + n0 + nn];
            ld[kk][nn + 0] = f2bf(x.x); ld[kk][nn + 1] = f2bf(x.y);
            ld[kk][nn + 2] = f2bf(x.z); ld[kk][nn + 3] = f2bf(x.w);
        }
    }
    __syncthreads();
    {
        const int n = t & 63, kc = (t >> 6) * 16;
        u16* op = wt + ((size_t)mat * 512 + n0 + n) * 512 + k0 + kc;
        #pragma unroll
        for (int j = 0; j < 4; ++j) {
            short4v v;
            v[0] = ld[kc + j*4 + 0][n]; v[1] = ld[kc + j*4 + 1][n];
            v[2] = ld[kc + j*4 + 2][n]; v[3] = ld[kc + j*4 + 3][n];
            *(short4v*)(op + j * 4) = v;
        }
    }
}

// ---------------- prep: mask int32 -> bit-packed u64 [8192 rows][32 words] ----------------
__global__ __launch_bounds__(256) void prepm_kernel(
    const int* __restrict__ mask, u64* __restrict__ bits)
{
    const int t = threadIdx.x;
    const int row = blockIdx.x * 4 + (t >> 6);
    const int wl = t & 63;
    const int* mrow = mask + (size_t)row * 2048;
    u64* brow = bits + (size_t)row * 32;
    #pragma unroll 8
    for (int it = 0; it < 32; ++it) {
        u64 b = __ballot(mrow[it * 64 + wl] != 0);
        if (wl == 0) brow[it] = b;
    }
}

// ---------------- K1: projections via MFMA. X fp32 @ Wt -> Qh/Kh bf16 [bh][s][64], V -> Vt [bh][64][2048]
__global__ __launch_bounds__(256) void proj_kernel(
    const float* __restrict__ qin, const float* __restrict__ kin, const float* __restrict__ vin,
    const u16* __restrict__ wt,
    u16* __restrict__ Qh, u16* __restrict__ Kh, u16* __restrict__ Vt)
{
    const int z = blockIdx.z;
    const float* X = z == 0 ? qin : (z == 1 ? kin : vin);
    const u16* W = wt + (size_t)z * 512 * 512;
    const int m0 = blockIdx.x * 64;
    const int h = blockIdx.y;
    const int t = threadIdx.x, l = t & 63, w = t >> 6;
    const int q = l & 15, G = l >> 4;
    const int wr = w >> 1, wc = w & 1;

    f32x4 acc[2][2] = {};
    for (int k0 = 0; k0 < 512; k0 += 32) {
        bf16x8 af[2], bfr[2];
        #pragma unroll
        for (int mi = 0; mi < 2; ++mi) {
            const float* xp = X + (size_t)(m0 + wr*32 + mi*16 + q) * 512 + k0 + G*8;
            float4 x0 = *(const float4*)xp;
            float4 x1 = *(const float4*)(xp + 4);
            bf16x8 a;
            a[0] = f2bf(x0.x); a[1] = f2bf(x0.y); a[2] = f2bf(x0.z); a[3] = f2bf(x0.w);
            a[4] = f2bf(x1.x); a[5] = f2bf(x1.y); a[6] = f2bf(x1.z); a[7] = f2bf(x1.w);
            af[mi] = a;
        }
        #pragma unroll
        for (int tn = 0; tn < 2; ++tn)
            bfr[tn] = *(const bf16x8*)(W + (size_t)(h*64 + wc*32 + tn*16 + q) * 512 + k0 + G*8);
        #pragma unroll
        for (int mi = 0; mi < 2; ++mi)
            #pragma unroll
            for (int tn = 0; tn < 2; ++tn)
                acc[mi][tn] = MFMA16(af[mi], bfr[tn], acc[mi][tn], 0, 0, 0);
    }
    if (z == 2) {
        // V: write transposed directly -> Vt[bh][d][s], 4 consecutive s per lane (8B)
        #pragma unroll
        for (int mi = 0; mi < 2; ++mi)
            #pragma unroll
            for (int tn = 0; tn < 2; ++tn) {
                const int d = wc*32 + tn*16 + q;
                const int m = m0 + wr*32 + mi*16 + G*4;
                const int bb = m >> 11, s = m & 2047;
                short4v sv;
                #pragma unroll
                for (int r = 0; r < 4; ++r) sv[r] = (short)f2bf(acc[mi][tn][r]);
                *(short4v*)&Vt[(((size_t)(bb*8 + h) << 6) + d) * 2048 + s] = sv;
            }
    } else {
        u16* O = z == 0 ? Qh : Kh;
        const float scv = (z == 0) ? 0.125f : 1.0f;   // fold 1/sqrt(64) into Q (exact pow2)
        #pragma unroll
        for (int mi = 0; mi < 2; ++mi)
            #pragma unroll
            for (int tn = 0; tn < 2; ++tn)
                #pragma unroll
                for (int r = 0; r < 4; ++r) {
                    const int m = m0 + wr*32 + mi*16 + G*4 + r;
                    const int bb = m >> 11, s = m & 2047;
                    const int d = wc*32 + tn*16 + q;
                    O[(((size_t)(bb*8 + h) << 11) + s) * 64 + d] = f2bf(acc[mi][tn][r] * scv);
                }
    }
}

// ---------------- fused attn, two-phase: P1 rowsums (K LDS-staged); P2 recompute QK,
// write normalized f32 attn directly (in-loop 512B-burst flushes), PV. No Et buffer.
__global__ __launch_bounds__(256) void attnpv_kernel(
    const u16* __restrict__ Qh, const u16* __restrict__ Kh, const u16* __restrict__ Vt,
    const u64* __restrict__ bits,
    float* __restrict__ attn, u16* __restrict__ heads)
{
    const int j   = blockIdx.x;
    const int lid = (j & 7) * 128 + (j >> 3);     // XCD-contiguous bh ranges
    const int qt = lid & 31, bh = lid >> 5;
    const int b = bh >> 3, h = bh & 7;
    const int m0 = qt * 64;
    const int t = threadIdx.x, l = t & 63, w = t >> 6;
    const int q = l & 15, G = l >> 4;
    const int qrow = m0 + w*16 + q;
    __shared__ u16 kbuf[2][4096];          // 64x64 bf16 K tile, XOR-swizzled rows
    __shared__ u16 vbuf[2][4096];          // 64x64 bf16 V^T tile
    __shared__ u16 alds2[4][2048];         // per-wave 2x(16x64) E tiles
    __shared__ float sinv[64];
    u16* alds2w = alds2[w];

    const size_t qbase = (((size_t)bh << 11) + qrow) * 64;
    bf16x8 qf0 = *(const bf16x8*)(Qh + qbase + G*8);
    bf16x8 qf1 = *(const bf16x8*)(Qh + qbase + 32 + G*8);
    const u64* brow = bits + (((size_t)b << 11) + qrow) * 32;
    const int swz = (q & 7) << 3;

    // staging geometry: thread covers rows srow0 (i=0) and srow0+32 (i=1), 16B each
    const int srow0 = t >> 3;
    const int scol  = (t & 7) * 8;
    const u16* Kbase = Kh + (((size_t)bh << 11) * 64);
    const u16* Vbase = Vt + (((size_t)bh << 6) * 2048);
    const int eswz = (t * 8) ^ ((srow0 & 7) << 3);

    bf16x8 sk0, sk1, sv0, sv1;
    float rs = 0.f;

    // ======== phase 1: row sums (K only) ========
    {
        const u16* kp = Kbase + (size_t)srow0 * 64 + scol;
        sk0 = *(const bf16x8*)kp;
        sk1 = *(const bf16x8*)(kp + 32 * 64);
        *(bf16x8*)&kbuf[0][eswz]        = sk0;
        *(bf16x8*)&kbuf[0][2048 + eswz] = sk1;
    }
    __syncthreads();
    for (int kt = 0; kt < 32; ++kt) {
        const int cur = kt & 1;
        if (kt < 31) {
            const u16* kp = Kbase + (size_t)((kt + 1) * 64 + srow0) * 64 + scol;
            sk0 = *(const bf16x8*)kp;
            sk1 = *(const bf16x8*)(kp + 32 * 64);
        }
        f32x4 acc[4] = {};
        #pragma unroll
        for (int mt = 0; mt < 4; ++mt) {
            const int r = mt*16 + q;
            const int rsw = (r & 7) << 3;
            bf16x8 k0 = *(const bf16x8*)&kbuf[cur][(r*64 +      G*8) ^ rsw];
            bf16x8 k1 = *(const bf16x8*)&kbuf[cur][(r*64 + 32 + G*8) ^ rsw];
            acc[mt] = MFMA16(k0, qf0, acc[mt], 0, 0, 0);
            acc[mt] = MFMA16(k1, qf1, acc[mt], 0, 0, 0);
        }
        const u64 mw = brow[kt];
        #pragma unroll
        for (int mt = 0; mt < 4; ++mt)
            #pragma unroll
            for (int r = 0; r < 4; ++r) {
                const int c = mt*16 + G*4 + r;
                rs += ((mw >> c) & 1) ? 0.f : exp2f(acc[mt][r] * L2E);
            }
        if (kt < 31) {
            *(bf16x8*)&kbuf[cur ^ 1][eswz]        = sk0;
            *(bf16x8*)&kbuf[cur ^ 1][2048 + eswz] = sk1;
        }
        __syncthreads();
    }
    rs += __shfl_xor(rs, 16);
    rs += __shfl_xor(rs, 32);
    const float inv = 1.0f / rs;
    if (G == 0) sinv[w*16 + q] = inv;
    __syncthreads();

    // ======== phase 2: recompute QK, write normalized attn, PV ========
    f32x4 pacc[4] = {};
    {
        const u16* kp = Kbase + (size_t)srow0 * 64 + scol;
        sk0 = *(const bf16x8*)kp;
        sk1 = *(const bf16x8*)(kp + 32 * 64);
        const u16* vp = Vbase + (size_t)srow0 * 2048 + scol;
        sv0 = *(const bf16x8*)vp;
        sv1 = *(const bf16x8*)(vp + 32 * 2048);
        *(bf16x8*)&kbuf[0][eswz]        = sk0;
        *(bf16x8*)&kbuf[0][2048 + eswz] = sk1;
        *(bf16x8*)&vbuf[0][eswz]        = sv0;
        *(bf16x8*)&vbuf[0][2048 + eswz] = sv1;
    }
    __syncthreads();
    for (int kt = 0; kt < 32; ++kt) {
        const int cur = kt & 1;
        if (kt < 31) {
            const int n1 = (kt + 1) * 64;
            const u16* kp = Kbase + (size_t)(n1 + srow0) * 64 + scol;
            sk0 = *(const bf16x8*)kp;
            sk1 = *(const bf16x8*)(kp + 32 * 64);
            const u16* vp = Vbase + (size_t)srow0 * 2048 + n1 + scol;
            sv0 = *(const bf16x8*)vp;
            sv1 = *(const bf16x8*)(vp + 32 * 2048);
        }
        f32x4 acc[4] = {};
        #pragma unroll
        for (int mt = 0; mt < 4; ++mt) {
            const int r = mt*16 + q;
            const int rsw = (r & 7) << 3;
            bf16x8 k0 = *(const bf16x8*)&kbuf[cur][(r*64 +      G*8) ^ rsw];
            bf16x8 k1 = *(const bf16x8*)&kbuf[cur][(r*64 + 32 + G*8) ^ rsw];
            acc[mt] = MFMA16(k0, qf0, acc[mt], 0, 0, 0);
            acc[mt] = MFMA16(k1, qf1, acc[mt], 0, 0, 0);
        }
        const u64 mw = brow[kt];
        u16* A2 = alds2w + (kt & 1) * 1024;
        #pragma unroll
        for (int mt = 0; mt < 4; ++mt) {
            short4v sv;
            #pragma unroll
            for (int r = 0; r < 4; ++r) {
                const int c = mt*16 + G*4 + r;
                const float e = ((mw >> c) & 1) ? 0.f : exp2f(acc[mt][r] * L2E);
                sv[r] = (short)f2bf(e);
            }
            *(short4v*)&A2[(q*64 + mt*16 + G*4) ^ swz] = sv;
        }
        bf16x8 an0 = *(const bf16x8*)&A2[(q*64 +  0 + G*8) ^ swz];
        bf16x8 an1 = *(const bf16x8*)&A2[(q*64 + 32 + G*8) ^ swz];
        #pragma unroll
        for (int dmt = 0; dmt < 4; ++dmt) {
            const int r = dmt*16 + q;
            const int rsw = (r & 7) << 3;
            bf16x8 v0 = *(const bf16x8*)&vbuf[cur][(r*64 +      G*8) ^ rsw];
            bf16x8 v1 = *(const bf16x8*)&vbuf[cur][(r*64 + 32 + G*8) ^ rsw];
            pacc[dmt] = MFMA16(v0, an0, pacc[dmt], 0, 0, 0);
            pacc[dmt] = MFMA16(v1, an1, pacc[dmt], 0, 0, 0);
        }
        if (kt < 31) {
            const int nxt = cur ^ 1;
            *(bf16x8*)&kbuf[nxt][eswz]        = sk0;
            *(bf16x8*)&kbuf[nxt][2048 + eswz] = sk1;
            *(bf16x8*)&vbuf[nxt][eswz]        = sv0;
            *(bf16x8*)&vbuf[nxt][2048 + eswz] = sv1;
        }
        if (kt & 1) {
            // flush 2 staged kt tiles: per row, wave writes 512B contiguous (128 keys f32)
            const int ktg = kt >> 1;                 // 0..15
            const u16* A2f = alds2w + (l >> 5) * 1024;
            float* awbase = attn + ((((size_t)bh << 11) + m0 + w*16) << 11) + ktg*128 + l*2;
            #pragma unroll
            for (int r = 0; r < 16; ++r) {
                const float iv = sinv[w*16 + r];
                const u32 e2 = *(const u32*)&A2f[(r*64 + (l & 31)*2) ^ ((r & 7) << 3)];
                f32x2 o;
                o[0] = bf2f((u16)(e2 & 0xffffu)) * iv;
                o[1] = bf2f((u16)(e2 >> 16))     * iv;
                *(f32x2*)(awbase + (size_t)r * 2048) = o;
            }
        }
        __syncthreads();
    }
    #pragma unroll
    for (int dmt = 0; dmt < 4; ++dmt) {
        short4v sv;
        #pragma unroll
        for (int r = 0; r < 4; ++r) sv[r] = (short)f2bf(pacc[dmt][r] * inv);
        *(short4v*)&heads[(((size_t)b << 11) + qrow) * 512 + h*64 + dmt*16 + G*4] = sv;
    }
}

// ---------------- K4: out = heads(bf16) @ wo + q residual ----------------
__global__ __launch_bounds__(256) void outgemm_kernel(
    const u16* __restrict__ heads, const u16* __restrict__ wt,
    const float* __restrict__ qin, float* __restrict__ out)
{
    const int m0 = blockIdx.x * 64, n0b = blockIdx.y * 64;
    const int t = threadIdx.x, l = t & 63, w = t >> 6;
    const int q = l & 15, G = l >> 4;
    const int wr = w >> 1, wc = w & 1;
    const u16* W = wt + (size_t)3 * 512 * 512;
    f32x4 acc[2][2] = {};
    for (int k0 = 0; k0 < 512; k0 += 32) {
        bf16x8 af[2], bfr[2];
        #pragma unroll
        for (int mi = 0; mi < 2; ++mi)
            af[mi] = *(const bf16x8*)(heads + (size_t)(m0 + wr*32 + mi*16 + q) * 512 + k0 + G*8);
        #pragma unroll
        for (int tn = 0; tn < 2; ++tn)
            bfr[tn] = *(const bf16x8*)(W + (size_t)(n0b + wc*32 + tn*16 + q) * 512 + k0 + G*8);
        #pragma unroll
        for (int mi = 0; mi < 2; ++mi)
            #pragma unroll
            for (int tn = 0; tn < 2; ++tn)
                acc[mi][tn] = MFMA16(af[mi], bfr[tn], acc[mi][tn], 0, 0, 0);
    }
    #pragma unroll
    for (int mi = 0; mi < 2; ++mi)
        #pragma unroll
        for (int r = 0; r < 4; ++r) {
            const int m = m0 + wr*32 + mi*16 + G*4 + r;
            #pragma unroll
            for (int tn = 0; tn < 2; ++tn) {
                const int n = n0b + wc*32 + tn*16 + q;
                out[(size_t)m * 512 + n] = acc[mi][tn][r] + qin[(size_t)m * 512 + n];
            }
        }
}

// ---------------- K5: in-place row LayerNorm ----------------
__global__ __launch_bounds__(256) void ln_kernel(
    float* __restrict__ out, const float* __restrict__ g, const float* __restrict__ be)
{
    const int m = blockIdx.x;
    float* row = out + (size_t)m * 512;
    const int t = threadIdx.x;
    float2 v = ((const float2*)row)[t];
    float s  = block_sum256(v.x + v.y);
    float s2 = block_sum256(v.x * v.x + v.y * v.y);
    const float mu  = s * (1.0f / 512.0f);
    const float var = s2 * (1.0f / 512.0f) - mu * mu;
    const float inv = rsqrtf(var + LN_EPS);
    float2 gg = ((const float2*)g)[t];
    float2 bb = ((const float2*)be)[t];
    float2 r;
    r.x = (v.x - mu) * inv * gg.x + bb.x;
    r.y = (v.y - mu) * inv * gg.y + bb.y;
    ((float2*)row)[t] = r;
}

// ---------------- launch ----------------
extern "C" void kernel_launch(void* const* d_in, const int* in_sizes, int n_in,
                              void* d_out, int out_size, void* d_ws, size_t ws_size,
                              hipStream_t stream) {
    const float* q   = (const float*)d_in[0];
    const float* k   = (const float*)d_in[1];
    const float* v   = (const float*)d_in[2];
    const float* wq  = (const float*)d_in[3];
    const float* wk  = (const float*)d_in[4];
    const float* wv  = (const float*)d_in[5];
    const float* wo  = (const float*)d_in[6];
    const float* g   = (const float*)d_in[7];
    const float* be  = (const float*)d_in[8];
    const int*   msk = (const int*)d_in[9];

    float* out  = (float*)d_out;
    float* attn = out + (size_t)4 * 2048 * 512;

    const size_t nQKV = (size_t)32 * 2048 * 64;          // 4M u16 per tensor
    u16* Qh    = (u16*)d_ws;
    u16* Kh    = Qh + nQKV;
    u16* Vt    = Kh + nQKV;
    u16* heads = Vt + nQKV;
    u16* wt    = heads + (size_t)8192 * 512;
    u64* bits  = (u64*)(wt + (size_t)4 * 512 * 512);

    prepw_kernel  <<<dim3(8, 8, 4),    256, 0, stream>>>(wq, wk, wv, wo, wt);
    prepm_kernel  <<<dim3(2048),       256, 0, stream>>>(msk, bits);
    proj_kernel   <<<dim3(128, 8, 3),  256, 0, stream>>>(q, k, v, wt, Qh, Kh, Vt);
    attnpv_kernel <<<dim3(1024),       256, 0, stream>>>(Qh, Kh, Vt, bits, attn, heads);
    outgemm_kernel<<<dim3(128, 8),     256, 0, stream>>>(heads, wt, q, out);
    ln_kernel     <<<dim3(8192),       256, 0, stream>>>(out, g, be);
}